// Round 7
// baseline (666.457 us; speedup 1.0000x reference)
//
#include <hip/hip_runtime.h>
#include <hip/hip_bf16.h>

#define R_REL 2016
#define MROWS 16384
#define HDIM  1024
#define EDIM  768
#define TOPK  28
#define KSEL  31
#define CAP   48
#define NPAD  2048
#define MPADR 2048

typedef unsigned short u16;
typedef __attribute__((ext_vector_type(8))) short short8;
typedef __attribute__((ext_vector_type(4))) float f32x4;

__device__ inline float bf2f(u16 u) {
  unsigned x = ((unsigned)u) << 16; float f;
  __builtin_memcpy(&f, &x, 4); return f;
}
__device__ inline u16 f2bf(float f) {
  __hip_bfloat16 h = __float2bfloat16(f);
  u16 u; __builtin_memcpy(&u, &h, 2); return u;
}
__device__ inline void gl2lds16(const void* g, void* l) {
  __builtin_amdgcn_global_load_lds((const __attribute__((address_space(1))) unsigned int*)g,
                                   (__attribute__((address_space(3))) unsigned int*)l, 16, 0, 0);
}

// ================= bf16x3 (or x1) NT GEMM, 64x64 tile, 4 waves, z-batched ==================
template<int PLANES>
__global__ __launch_bounds__(256) void x3gemm(
    const u16* __restrict__ Ah0, const u16* __restrict__ Am0, const u16* __restrict__ Al0,
    const u16* __restrict__ Ah1, const u16* __restrict__ Am1, const u16* __restrict__ Al1,
    const u16* __restrict__ Bh, const u16* __restrict__ Bm, const u16* __restrict__ Bl,
    const float* __restrict__ bias0, const float* __restrict__ bias1,
    float* __restrict__ C0, float* __restrict__ C1,
    int K, int Nstride, int Mlim, int Nlim)
{
  __shared__ u16 lA[PLANES][64 * 32];
  __shared__ u16 lB[PLANES][64 * 32];
  const int zz = blockIdx.z;
  const u16* Ap[3] = { zz ? Ah1 : Ah0, zz ? Am1 : Am0, zz ? Al1 : Al0 };
  const u16* Bp[3] = {Bh, Bm, Bl};
  const float* bias = zz ? bias1 : bias0;
  float* C = zz ? C1 : C0;
  const int tid = threadIdx.x;
  const int wave = tid >> 6, lane = tid & 63;
  const int wr = wave >> 1, wc = wave & 1;
  const int row0 = blockIdx.y * 64, col0 = blockIdx.x * 64;

  f32x4 acc[2][2];
#pragma unroll
  for (int m = 0; m < 2; ++m)
#pragma unroll
    for (int n = 0; n < 2; ++n) acc[m][n] = (f32x4){0.f, 0.f, 0.f, 0.f};

  const int srow = lane >> 2, sslot = lane & 3;
  const int r15 = lane & 15, kq = lane >> 4;

  for (int k0 = 0; k0 < K; k0 += 32) {
    const int row = wave * 16 + srow;
    const int kg = sslot ^ ((row >> 1) & 3);
#pragma unroll
    for (int p = 0; p < PLANES; ++p) {
      gl2lds16(Ap[p] + (size_t)(row0 + row) * K + k0 + kg * 8, (u16*)lA[p] + wave * 512);
      gl2lds16(Bp[p] + (size_t)(col0 + row) * K + k0 + kg * 8, (u16*)lB[p] + wave * 512);
    }
    __syncthreads();
    short8 a[PLANES][2], b[PLANES][2];
#pragma unroll
    for (int m = 0; m < 2; ++m) {
      const int rowL = wr * 32 + m * 16 + r15;
      const int slot = kq ^ ((rowL >> 1) & 3);
#pragma unroll
      for (int p = 0; p < PLANES; ++p)
        a[p][m] = *reinterpret_cast<const short8*>(&lA[p][rowL * 32 + slot * 8]);
    }
#pragma unroll
    for (int n = 0; n < 2; ++n) {
      const int colL = wc * 32 + n * 16 + r15;
      const int slot = kq ^ ((colL >> 1) & 3);
#pragma unroll
      for (int p = 0; p < PLANES; ++p)
        b[p][n] = *reinterpret_cast<const short8*>(&lB[p][colL * 32 + slot * 8]);
    }
#pragma unroll
    for (int m = 0; m < 2; ++m)
#pragma unroll
      for (int n = 0; n < 2; ++n) {
        if constexpr (PLANES == 3) {
          acc[m][n] = __builtin_amdgcn_mfma_f32_16x16x32_bf16(a[2][m], b[0][n], acc[m][n], 0, 0, 0);
          acc[m][n] = __builtin_amdgcn_mfma_f32_16x16x32_bf16(a[0][m], b[2][n], acc[m][n], 0, 0, 0);
          acc[m][n] = __builtin_amdgcn_mfma_f32_16x16x32_bf16(a[1][m], b[1][n], acc[m][n], 0, 0, 0);
          acc[m][n] = __builtin_amdgcn_mfma_f32_16x16x32_bf16(a[1][m], b[0][n], acc[m][n], 0, 0, 0);
          acc[m][n] = __builtin_amdgcn_mfma_f32_16x16x32_bf16(a[0][m], b[1][n], acc[m][n], 0, 0, 0);
          acc[m][n] = __builtin_amdgcn_mfma_f32_16x16x32_bf16(a[0][m], b[0][n], acc[m][n], 0, 0, 0);
        } else {
          acc[m][n] = __builtin_amdgcn_mfma_f32_16x16x32_bf16(a[0][m], b[0][n], acc[m][n], 0, 0, 0);
        }
      }
    __syncthreads();
  }
  const int quad = lane >> 4;
#pragma unroll
  for (int m = 0; m < 2; ++m)
#pragma unroll
    for (int n = 0; n < 2; ++n) {
      const int cg = col0 + wc * 32 + n * 16 + r15;
      if (cg >= Nlim) continue;
      const float ev = bias ? bias[cg] : 0.f;
#pragma unroll
      for (int reg = 0; reg < 4; ++reg) {
        const int rg = row0 + wr * 32 + m * 16 + quad * 4 + reg;
        if (rg < Mlim) C[(size_t)rg * Nstride + cg] = acc[m][n][reg] + ev;
      }
    }
}

// ============ scores MFMA (128x128, BK=32, XCD-swizzled): Kt = key((A@B^T + cvec)/32) ======
__global__ __launch_bounds__(256) void mfma_scores128(
    const u16* __restrict__ A, const u16* __restrict__ B,
    const float* __restrict__ cvec, u16* __restrict__ Kt, int K, int Nlim)
{
  __shared__ u16 ldsA[128 * 32];
  __shared__ u16 ldsB[128 * 32];
  const int tid = threadIdx.x;
  const int wave = tid >> 6, lane = tid & 63;
  const int wr = wave >> 1, wc = wave & 1;
  unsigned wg = blockIdx.y * gridDim.x + blockIdx.x;
  const unsigned per = (gridDim.x * gridDim.y) >> 3;
  wg = (wg & 7) * per + (wg >> 3);
  const int row0 = (int)(wg / gridDim.x) * 128, col0 = (int)(wg % gridDim.x) * 128;

  f32x4 acc[4][4];
#pragma unroll
  for (int m = 0; m < 4; ++m)
#pragma unroll
    for (int n = 0; n < 4; ++n) acc[m][n] = (f32x4){0.f, 0.f, 0.f, 0.f};

  const int srow = lane >> 2, sslot = lane & 3;

  for (int k0 = 0; k0 < K; k0 += 32) {
#pragma unroll
    for (int j = 0; j < 2; ++j) {
      const int row = (wave * 2 + j) * 16 + srow;
      const int kg = sslot ^ ((row >> 1) & 3);
      gl2lds16(A + (size_t)(row0 + row) * K + k0 + kg * 8, (char*)ldsA + (size_t)(wave * 2 + j) * 1024);
      gl2lds16(B + (size_t)(col0 + row) * K + k0 + kg * 8, (char*)ldsB + (size_t)(wave * 2 + j) * 1024);
    }
    __syncthreads();
    const int r15 = lane & 15, kq = lane >> 4;
    short8 a[4], b[4];
#pragma unroll
    for (int m = 0; m < 4; ++m) {
      const int rowL = wr * 64 + m * 16 + r15;
      const int slot = kq ^ ((rowL >> 1) & 3);
      a[m] = *reinterpret_cast<const short8*>(&ldsA[rowL * 32 + slot * 8]);
    }
#pragma unroll
    for (int n = 0; n < 4; ++n) {
      const int colL = wc * 64 + n * 16 + r15;
      const int slot = kq ^ ((colL >> 1) & 3);
      b[n] = *reinterpret_cast<const short8*>(&ldsB[colL * 32 + slot * 8]);
    }
#pragma unroll
    for (int m = 0; m < 4; ++m)
#pragma unroll
      for (int n = 0; n < 4; ++n)
        acc[m][n] = __builtin_amdgcn_mfma_f32_16x16x32_bf16(a[m], b[n], acc[m][n], 0, 0, 0);
    __syncthreads();
  }
  const int r15 = lane & 15, quad = lane >> 4;
#pragma unroll
  for (int m = 0; m < 4; ++m)
#pragma unroll
    for (int n = 0; n < 4; ++n) {
      const int cg = col0 + wc * 64 + n * 16 + r15;
      if (cg >= Nlim) continue;
      const float cv = cvec[cg];
#pragma unroll
      for (int reg = 0; reg < 4; ++reg) {
        const int rg = row0 + wr * 64 + m * 16 + quad * 4 + reg;
        const float s = (acc[m][n][reg] + cv) * 0.03125f;
        const u16 u = f2bf(s);
        const u16 key = (u & 0x8000) ? (u16)(~u) : (u16)(u | 0x8000);
        Kt[(size_t)rg * NPAD + cg] = key;
      }
    }
}

// ================= decompose / conv helpers =================
__global__ __launch_bounds__(256) void decompose3(
    const float* __restrict__ in, u16* __restrict__ H, u16* __restrict__ M, u16* __restrict__ L,
    long n4_total, long n4_valid)
{
  for (long i = blockIdx.x * 256 + threadIdx.x; i < n4_total; i += (long)gridDim.x * 256) {
    u16 oh[4] = {0,0,0,0}, om[4] = {0,0,0,0}, ol[4] = {0,0,0,0};
    if (i < n4_valid) {
      const float4 f = *reinterpret_cast<const float4*>(in + i * 4);
      const float xs[4] = {f.x, f.y, f.z, f.w};
#pragma unroll
      for (int t = 0; t < 4; ++t) {
        const float x = xs[t];
        const u16 h = f2bf(x);       const float r1 = x - bf2f(h);
        const u16 m = f2bf(r1);      const float r2 = r1 - bf2f(m);
        const u16 l = f2bf(r2);
        oh[t] = h; om[t] = m; ol[t] = l;
      }
    }
    *reinterpret_cast<ulong1*>(H + i * 4) = *reinterpret_cast<ulong1*>(oh);
    *reinterpret_cast<ulong1*>(M + i * 4) = *reinterpret_cast<ulong1*>(om);
    *reinterpret_cast<ulong1*>(L + i * 4) = *reinterpret_cast<ulong1*>(ol);
  }
}

// z-batched transpose-decompose: z picks (in, out-planes). [R,C] f32 -> [C,R] bf16 x3.
__global__ __launch_bounds__(256) void decomposeT2(
    const float* __restrict__ in0, u16* __restrict__ H0, u16* __restrict__ M0, u16* __restrict__ L0,
    const float* __restrict__ in1, u16* __restrict__ H1, u16* __restrict__ M1, u16* __restrict__ L1,
    int R, int C)
{
  __shared__ float t[32][33];
  const float* in = blockIdx.z ? in1 : in0;
  u16* H = blockIdx.z ? H1 : H0;
  u16* M = blockIdx.z ? M1 : M0;
  u16* L = blockIdx.z ? L1 : L0;
  const int x = threadIdx.x & 31, y = threadIdx.x >> 5;
  const int bx = blockIdx.x, by = blockIdx.y;
#pragma unroll
  for (int yy = 0; yy < 4; ++yy)
    t[y + yy * 8][x] = in[(size_t)(by * 32 + y + yy * 8) * C + bx * 32 + x];
  __syncthreads();
#pragma unroll
  for (int yy = 0; yy < 4; ++yy) {
    const float v = t[x][y + yy * 8];
    const u16 h = f2bf(v);      const float r1 = v - bf2f(h);
    const u16 m = f2bf(r1);     const float r2 = r1 - bf2f(m);
    const u16 l = f2bf(r2);
    const size_t o = (size_t)(bx * 32 + y + yy * 8) * R + by * 32 + x;
    H[o] = h; M[o] = m; L[o] = l;
  }
}

// two-segment f32->bf16 conversion (zero-pad beyond valid)
__global__ __launch_bounds__(256) void conv2seg(
    const float* __restrict__ inA, u16* __restrict__ outA, long nb_a, long n4a_valid,
    const float* __restrict__ inB, u16* __restrict__ outB)
{
  const long b = blockIdx.x;
  const float* in; u16* out; long i;
  bool valid = true;
  if (b < nb_a) { in = inA; out = outA; i = b * 256 + threadIdx.x; valid = (i < n4a_valid); }
  else          { in = inB; out = outB; i = (b - nb_a) * 256 + threadIdx.x; }
  u16 o[4] = {0, 0, 0, 0};
  if (valid) {
    const float4 f = *reinterpret_cast<const float4*>(in + i * 4);
    o[0] = f2bf(f.x); o[1] = f2bf(f.y); o[2] = f2bf(f.z); o[3] = f2bf(f.w);
  }
  *reinterpret_cast<ulong1*>(out + i * 4) = *reinterpret_cast<ulong1*>(o);
}

__global__ __launch_bounds__(256) void conv_bf16(
    const float* __restrict__ in, u16* __restrict__ out, long n4)
{
  for (long i = blockIdx.x * 256 + threadIdx.x; i < n4; i += (long)gridDim.x * 256) {
    const float4 f = *reinterpret_cast<const float4*>(in + i * 4);
    u16 o[4] = {f2bf(f.x), f2bf(f.y), f2bf(f.z), f2bf(f.w)};
    *reinterpret_cast<ulong1*>(out + i * 4) = *reinterpret_cast<ulong1*>(o);
  }
}

// ================= bias-vector prologue kernels =================
// b<256: u1[row] = Wk^T.bq ; else: cvv[row] = Wv[row,:].bt + bv[row]
__global__ __launch_bounds__(256) void dual_rowdot(
    const float* __restrict__ Wk, const float* __restrict__ bq,
    const float* __restrict__ Wv, const float* __restrict__ bt, const float* __restrict__ bv,
    float* __restrict__ u1, float* __restrict__ cvv)
{
  const int b = blockIdx.x;
  const int row = (b & 255) * 4 + (threadIdx.x >> 6);
  const int lane = threadIdx.x & 63;
  float acc = 0.f;
  if (b < 256) {
#pragma unroll
    for (int j = 0; j < 16; ++j)
      acc = fmaf(Wk[row + (size_t)(lane + j * 64) * HDIM], bq[lane + j * 64], acc);
  } else {
#pragma unroll
    for (int j = 0; j < 16; ++j)
      acc = fmaf(Wv[(size_t)row * HDIM + lane + j * 64], bt[lane + j * 64], acc);
  }
#pragma unroll
  for (int off = 32; off; off >>= 1) acc += __shfl_xor(acc, off);
  if (lane == 0) {
    if (b < 256) u1[row] = acc;
    else cvv[row] = acc + bv[row];
  }
}

// u2[j] = Wt^T.u1  (j < 768)
__global__ __launch_bounds__(256) void u2_k(
    const float* __restrict__ Wt, const float* __restrict__ u1, float* __restrict__ u2)
{
  const int row = blockIdx.x * 4 + (threadIdx.x >> 6);
  const int lane = threadIdx.x & 63;
  float acc = 0.f;
#pragma unroll
  for (int j = 0; j < 16; ++j)
    acc = fmaf(Wt[row + (size_t)(lane + j * 64) * EDIM], u1[lane + j * 64], acc);
#pragma unroll
  for (int off = 32; off; off >>= 1) acc += __shfl_xor(acc, off);
  if (lane == 0) u2[row] = acc;
}

// cvec[r] = rel[r,:].u2 + (bt.u1 + bk.bq)
__global__ __launch_bounds__(256) void cvec_k(
    const float* __restrict__ rel, const float* __restrict__ u2,
    const float* __restrict__ u1, const float* __restrict__ bt,
    const float* __restrict__ bk, const float* __restrict__ bq, float* __restrict__ cvec)
{
  const int row = blockIdx.x * 4 + (threadIdx.x >> 6);
  const int lane = threadIdx.x & 63;
  if (row >= R_REL) return;
  float acc = 0.f;
#pragma unroll
  for (int j = 0; j < 12; ++j)
    acc = fmaf(rel[(size_t)row * EDIM + lane + j * 64], u2[lane + j * 64], acc);
  float sac = 0.f;
#pragma unroll
  for (int j = 0; j < 16; ++j) {
    const int k = lane + j * 64;
    sac = fmaf(bt[k], u1[k], sac);
    sac = fmaf(bk[k], bq[k], sac);
  }
  acc += sac;
#pragma unroll
  for (int off = 32; off; off >>= 1) acc += __shfl_xor(acc, off);
  if (lane == 0) cvec[row] = acc;
}

// w2bias[j] = T1f[j,:].bt + Wq[:,j].bk
__global__ __launch_bounds__(256) void w2bias_k(
    const float* __restrict__ T1f, const float* __restrict__ Wq,
    const float* __restrict__ bt, const float* __restrict__ bk, float* __restrict__ w2bias)
{
  const int row = blockIdx.x * 4 + (threadIdx.x >> 6);
  const int lane = threadIdx.x & 63;
  float acc = 0.f;
#pragma unroll
  for (int j = 0; j < 16; ++j) {
    const int k = lane + j * 64;
    acc = fmaf(T1f[(size_t)row * HDIM + k], bt[k], acc);
    acc = fmaf(Wq[row + (size_t)k * HDIM], bk[k], acc);
  }
#pragma unroll
  for (int off = 32; off; off >>= 1) acc += __shfl_xor(acc, off);
  if (lane == 0) w2bias[row] = acc;
}

// ================= fbits (self-detecting mask kind) + fij pack =================
__global__ __launch_bounds__(256) void build_fbits(
    const void* __restrict__ mask, const int* __restrict__ f_i, const int* __restrict__ f_j,
    unsigned long long* __restrict__ fbits, unsigned* __restrict__ fij)
{
  const int gm = blockIdx.x * 4 + (threadIdx.x >> 6);
  const int lane = threadIdx.x & 63;
  // self-detect kind from first 256 words: f32 marker wins, then byte-bools, else int32
  const unsigned* mw = (const unsigned*)mask;
  bool sawf = false, sawg = false;
#pragma unroll
  for (int t = 0; t < 4; ++t) {
    const unsigned w = mw[lane * 4 + t];
    sawf |= (w == 0x3F800000u);
    sawg |= (w > 1u);
  }
  const int kind = __ballot(sawf) ? 2 : (__ballot(sawg) ? 1 : 0);
  const size_t e = (size_t)gm * 64 + lane;
  bool on;
  if (kind == 0)      on = ((const int*)mask)[e] != 0;
  else if (kind == 1) on = ((const unsigned char*)mask)[e] != 0;
  else                on = ((const float*)mask)[e] != 0.f;
  const unsigned long long b = __ballot(on);
  if (lane == 0) fbits[gm] = b;
  if (blockIdx.x < 8) {
    const int i = blockIdx.x * 256 + threadIdx.x;
    const int src = (i < R_REL) ? i : (R_REL - 1);
    fij[i] = ((unsigned)f_i[src] & 0xFFFFu) | (((unsigned)f_j[src] & 0xFFFFu) << 16);
  }
}

// ====== FUSED: radix prefilter + serial exact f32 rescore + bitonic top-28 + softmax + V-gather ======
__global__ __launch_bounds__(64) void topk_gather(
    const u16* __restrict__ Kt, const unsigned long long* __restrict__ fbits,
    const unsigned* __restrict__ fij,
    const float* __restrict__ qh, const float* __restrict__ W2, const float* __restrict__ cvec,
    const float* __restrict__ Vm, float* __restrict__ out)
{
  const int gm = blockIdx.x;
  const int lane = threadIdx.x;
  const unsigned long long fb = fbits[gm];
  __shared__ int cand[CAP];

  unsigned key[32];
  const u16* rowp = Kt + (size_t)gm * NPAD;
#pragma unroll
  for (int L = 0; L < 4; ++L) {
    const int rrb = lane * 8 + L * 512;
    const short8 v = *reinterpret_cast<const short8*>(rowp + rrb);
    const uint4 p0 = *reinterpret_cast<const uint4*>(fij + rrb);
    const uint4 p1 = *reinterpret_cast<const uint4*>(fij + rrb + 4);
    const unsigned ps[8] = {p0.x, p0.y, p0.z, p0.w, p1.x, p1.y, p1.z, p1.w};
#pragma unroll
    for (int r = 0; r < 8; ++r) {
      const int rr = rrb + r;
      const unsigned p = ps[r];
      const bool act = (rr < R_REL) &&
        ((((fb >> (p & 63u)) & (fb >> (p >> 16))) & 1ULL) != 0);
      key[L * 8 + r] = act ? (unsigned)(u16)v[r] : 0u;
    }
  }

  // binary search largest T with count(key >= T) >= KSEL
  int lo = 1, hi = 65536;
  while (hi - lo > 1) {
    const int mid = (lo + hi) >> 1;
    int cnt = 0;
#pragma unroll
    for (int j = 0; j < 32; ++j)
      cnt += __popcll(__ballot(key[j] >= (unsigned)mid));
    if (cnt >= KSEL) lo = mid; else hi = mid;
  }
  const unsigned T = (unsigned)lo;

  // extract candidates (deterministic order), capped at CAP
  int base = 0;
#pragma unroll
  for (int L = 0; L < 4; ++L) {
#pragma unroll
    for (int r = 0; r < 8; ++r) {
      const int j = L * 8 + r;
      const bool c = key[j] >= T;
      const unsigned long long m = __ballot(c);
      const int pre = __builtin_amdgcn_mbcnt_hi((unsigned)(m >> 32),
                      __builtin_amdgcn_mbcnt_lo((unsigned)m, 0));
      const int slot = base + pre;
      if (c && slot < CAP) cand[slot] = lane * 8 + r + L * 512;
      base += __popcll(m);
    }
  }
  const int ncand = (base < CAP) ? base : CAP;
  __syncthreads();

  // exact f32 rescore, one candidate at a time (L1 keeps the row across v4 steps)
  float q[16];
  {
    const float* qp = qh + (size_t)gm * HDIM + lane * 16;
#pragma unroll
    for (int v4 = 0; v4 < 4; ++v4) {
      const float4 f = *reinterpret_cast<const float4*>(qp + v4 * 4);
      q[v4 * 4 + 0] = f.x; q[v4 * 4 + 1] = f.y; q[v4 * 4 + 2] = f.z; q[v4 * 4 + 3] = f.w;
    }
  }
  float myscore = -INFINITY;
  for (int c = 0; c < CAP; ++c) {
    if (c >= ncand) break;
    const int r = cand[c];
    const float* wp = W2 + (size_t)r * HDIM + lane * 16;
    float d = 0.f;
#pragma unroll
    for (int v4 = 0; v4 < 4; ++v4) {
      const float4 f = *reinterpret_cast<const float4*>(wp + v4 * 4);
      d = fmaf(q[v4 * 4 + 0], f.x, d);
      d = fmaf(q[v4 * 4 + 1], f.y, d);
      d = fmaf(q[v4 * 4 + 2], f.z, d);
      d = fmaf(q[v4 * 4 + 3], f.w, d);
    }
#pragma unroll
    for (int off = 32; off; off >>= 1) d += __shfl_xor(d, off);
    const float s = (d + cvec[r]) * 0.03125f;
    if (lane == c) myscore = s;
  }
  int myr = 0x7fffffff;
  if (lane < ncand) myr = cand[lane];

  // bitonic sort 64 lanes, descending score, tie -> ascending index
#pragma unroll
  for (int k = 2; k <= 64; k <<= 1) {
#pragma unroll
    for (int j = k >> 1; j > 0; j >>= 1) {
      const float ov = __shfl_xor(myscore, j);
      const int oi = __shfl_xor(myr, j);
      const bool lower = (lane & j) == 0;
      const bool want_desc = (lane & k) == 0;
      const bool mine_better = (myscore > ov) || (myscore == ov && myr < oi);
      const bool keep = (lower == want_desc) ? mine_better : !mine_better;
      if (!keep) { myscore = ov; myr = oi; }
    }
  }

  const int nvalid = __popcll(__ballot(myscore > -INFINITY));
  const int nsel = (nvalid < TOPK) ? nvalid : TOPK;
  const float m0 = __shfl(myscore, 0);
  const float e = (lane < nsel) ? expf(myscore - m0) : 0.f;
  float z = e;
#pragma unroll
  for (int off = 32; off; off >>= 1) z += __shfl_xor(z, off);
  const float w_own = (lane < nsel) ? (e / z) : 0.f;

  // gather: out[gm, lane*4 + j*256] = sum_i w_i * Vm[r_i, ...]  (coalesced 1KB/instr)
  float4 o0 = {0,0,0,0}, o1 = {0,0,0,0}, o2 = {0,0,0,0}, o3 = {0,0,0,0};
  for (int i = 0; i < TOPK; ++i) {
    if (i >= nsel) break;
    const float wi = __shfl(w_own, i);
    const int ri = __shfl(myr, i);
    const float* vp = Vm + (size_t)ri * HDIM + lane * 4;
    const float4 v0 = *reinterpret_cast<const float4*>(vp);
    const float4 v1 = *reinterpret_cast<const float4*>(vp + 256);
    const float4 v2 = *reinterpret_cast<const float4*>(vp + 512);
    const float4 v3 = *reinterpret_cast<const float4*>(vp + 768);
    o0.x = fmaf(wi, v0.x, o0.x); o0.y = fmaf(wi, v0.y, o0.y);
    o0.z = fmaf(wi, v0.z, o0.z); o0.w = fmaf(wi, v0.w, o0.w);
    o1.x = fmaf(wi, v1.x, o1.x); o1.y = fmaf(wi, v1.y, o1.y);
    o1.z = fmaf(wi, v1.z, o1.z); o1.w = fmaf(wi, v1.w, o1.w);
    o2.x = fmaf(wi, v2.x, o2.x); o2.y = fmaf(wi, v2.y, o2.y);
    o2.z = fmaf(wi, v2.z, o2.z); o2.w = fmaf(wi, v2.w, o2.w);
    o3.x = fmaf(wi, v3.x, o3.x); o3.y = fmaf(wi, v3.y, o3.y);
    o3.z = fmaf(wi, v3.z, o3.z); o3.w = fmaf(wi, v3.w, o3.w);
  }
  float* op = out + (size_t)gm * HDIM + lane * 4;
  *reinterpret_cast<float4*>(op)       = o0;
  *reinterpret_cast<float4*>(op + 256) = o1;
  *reinterpret_cast<float4*>(op + 512) = o2;
  *reinterpret_cast<float4*>(op + 768) = o3;
}

extern "C" void kernel_launch(void* const* d_in, const int* in_sizes, int n_in,
                              void* d_out, int out_size, void* d_ws, size_t ws_size,
                              hipStream_t stream) {
  const float* qh  = (const float*)d_in[0];
  const void*  mask = d_in[1];
  const float* rel = (const float*)d_in[2];
  const int* f_i = (const int*)d_in[3];
  const int* f_j = (const int*)d_in[4];
  const float* Wt = (const float*)d_in[5]; const float* bt = (const float*)d_in[6];
  const float* Wq = (const float*)d_in[7]; const float* bq = (const float*)d_in[8];
  const float* Wk = (const float*)d_in[9]; const float* bk = (const float*)d_in[10];
  const float* Wv = (const float*)d_in[11]; const float* bv = (const float*)d_in[12];
  float* out = (float*)d_out;

  // ---- workspace layout with lifetime-based aliasing ----
  char* p = (char*)d_ws;
  auto alloc = [&](size_t bytes) { char* q_ = p; p += (bytes + 255) & ~(size_t)255; return q_; };
  float* W2   = (float*)alloc((size_t)R_REL * HDIM * 4);
  char* strip = alloc((size_t)(1024*1024 + 1024*768 + 1024*768) * 4);
  float* T1f = (float*)strip;
  float* Pf  = T1f + 1024 * 1024;
  float* Pvf = Pf + 1024 * 768;
  float* Vm  = (float*)strip;                   // alias (written after T1f/Pf/Pvf dead)
  u16* R1 = (u16*)alloc((size_t)3 * 1024 * 1024 * 2);   // WqT planes -> T1 planes
  u16* R2 = (u16*)alloc((size_t)3 * 1024 * 1024 * 2);   // WkT planes -> P planes
  u16* WtTp = (u16*)alloc((size_t)3 * 768 * 1024 * 2);
  u16* relp = (u16*)alloc((size_t)3 * MPADR * EDIM * 2);
  u16* qhb  = (u16*)alloc((size_t)MROWS * HDIM * 2);
  u16* W2b  = (u16*)alloc((size_t)NPAD * HDIM * 2);
  u16* Pv16 = (u16*)alloc((size_t)1024 * 768 * 2);
  u16* Kt   = (u16*)alloc((size_t)MROWS * NPAD * 2);
  u16* R3   = Kt;                               // Wv planes (dead before Kt written)
  float* cvec   = (float*)alloc(NPAD * 4);
  float* u1     = (float*)alloc(1024 * 4);
  float* u2     = (float*)alloc(1024 * 4);
  float* w2bias = (float*)alloc(1024 * 4);
  float* cvv    = (float*)alloc(1024 * 4);
  unsigned long long* fbits = (unsigned long long*)alloc((size_t)MROWS * 8);
  unsigned* fij = (unsigned*)alloc(NPAD * 4);

  const size_t PL1 = (size_t)1024 * 1024;
  const size_t PLW = (size_t)768 * 1024;
  const size_t PLR = (size_t)MPADR * EDIM;
  const size_t PLP = (size_t)1024 * 768;

  const dim3 blk(256);

  // fbits (self-detecting) + fij
  build_fbits<<<dim3(MROWS / 4), blk, 0, stream>>>(mask, f_i, f_j, fbits, fij);

  // weight decompositions
  decomposeT2<<<dim3(1024/32, 1024/32, 2), blk, 0, stream>>>(
      Wq, R1, R1+PL1, R1+2*PL1, Wk, R2, R2+PL1, R2+2*PL1, 1024, 1024);
  decomposeT2<<<dim3(768/32, 1024/32, 1), blk, 0, stream>>>(
      Wt, WtTp, WtTp+PLW, WtTp+2*PLW, nullptr, nullptr, nullptr, nullptr, 1024, 768);
  decompose3<<<dim3(1024), blk, 0, stream>>>(rel, relp, relp+PLR, relp+2*PLR,
                                             (long)MPADR*EDIM/4, (long)R_REL*EDIM/4);
  decompose3<<<dim3(1024), blk, 0, stream>>>(Wv, R3, R3+PL1, R3+2*PL1, (long)PL1/4, (long)PL1/4);
  conv_bf16<<<dim3(2048), blk, 0, stream>>>(qh, qhb, (long)MROWS*HDIM/4);

  // bias-vector chain
  dual_rowdot<<<dim3(512), blk, 0, stream>>>(Wk, bq, Wv, bt, bv, u1, cvv);
  u2_k<<<dim3(192), blk, 0, stream>>>(Wt, u1, u2);
  cvec_k<<<dim3((R_REL + 3) / 4), blk, 0, stream>>>(rel, u2, u1, bt, bk, bq, cvec);

  // T1 = Wq^T @ Wk  (bf16x3)
  x3gemm<3><<<dim3(1024/64, 1024/64, 1), blk, 0, stream>>>(
      R1, R1+PL1, R1+2*PL1, nullptr, nullptr, nullptr,
      R2, R2+PL1, R2+2*PL1, nullptr, nullptr, T1f, nullptr, 1024, 1024, 1024, 1024);
  w2bias_k<<<dim3(256), blk, 0, stream>>>(T1f, Wq, bt, bk, w2bias);
  decompose3<<<dim3(1024), blk, 0, stream>>>(T1f, R1, R1+PL1, R1+2*PL1, (long)PL1/4, (long)PL1/4);
  // P = T1 @ Wt  and  Pv = Wv @ Wt  (z-batched, shared B = WtT planes)
  x3gemm<3><<<dim3(768/64, 1024/64, 2), blk, 0, stream>>>(
      R1, R1+PL1, R1+2*PL1, R3, R3+PL1, R3+2*PL1,
      WtTp, WtTp+PLW, WtTp+2*PLW, nullptr, nullptr, Pf, Pvf, 1024, 768, 1024, 768);
  decompose3<<<dim3(1024), blk, 0, stream>>>(Pf, R2, R2+PLP, R2+2*PLP, (long)PLP/4, (long)PLP/4);
  // W2 = rel @ P^T + w2bias
  x3gemm<3><<<dim3(1024/64, MPADR/64, 1), blk, 0, stream>>>(
      relp, relp+PLR, relp+2*PLR, nullptr, nullptr, nullptr,
      R2, R2+PLP, R2+2*PLP, w2bias, nullptr, W2, nullptr, EDIM, HDIM, R_REL, HDIM);

  // W2b (padded) + Pv16 conversions in one launch
  conv2seg<<<dim3(2048 + 768), blk, 0, stream>>>(
      W2, W2b, 2048, (long)R_REL*HDIM/4, Pvf, Pv16);

  // Vm = rel_h @ Pv16^T + cvv  (bf16; aliases the dead f32 strip)
  x3gemm<1><<<dim3(1024/64, MPADR/64, 1), blk, 0, stream>>>(
      relp, nullptr, nullptr, nullptr, nullptr, nullptr,
      Pv16, nullptr, nullptr, cvv, nullptr, Vm, nullptr, EDIM, HDIM, R_REL, HDIM);

  // approx score keys (overwrites R3 region — Wv planes dead)
  mfma_scores128<<<dim3(NPAD/128, MROWS/128), blk, 0, stream>>>(qhb, W2b, cvec, Kt, HDIM, R_REL);

  // fused prefilter + exact rescore + top-28 + softmax + V-gather
  topk_gather<<<dim3(MROWS), dim3(64), 0, stream>>>(Kt, fbits, fij, qh, W2, cvec, Vm, out);
}

// Round 8
// 609.517 us; speedup vs baseline: 1.0934x; 1.0934x over previous
//
#include <hip/hip_runtime.h>
#include <hip/hip_bf16.h>

#define R_REL 2016
#define MROWS 16384
#define HDIM  1024
#define EDIM  768
#define TOPK  28
#define KSEL  31
#define CAP   48
#define NPAD  2048
#define MPADR 2048

typedef unsigned short u16;
typedef __attribute__((ext_vector_type(8))) short short8;
typedef __attribute__((ext_vector_type(4))) float f32x4;

__device__ inline float bf2f(u16 u) {
  unsigned x = ((unsigned)u) << 16; float f;
  __builtin_memcpy(&f, &x, 4); return f;
}
__device__ inline u16 f2bf(float f) {
  __hip_bfloat16 h = __float2bfloat16(f);
  u16 u; __builtin_memcpy(&u, &h, 2); return u;
}
__device__ inline void gl2lds16(const void* g, void* l) {
  __builtin_amdgcn_global_load_lds((const __attribute__((address_space(1))) unsigned int*)g,
                                   (__attribute__((address_space(3))) unsigned int*)l, 16, 0, 0);
}

// ================= bf16x3 (or x1) NT GEMM, 64x64 tile, 4 waves, z-batched ==================
template<int PLANES>
__global__ __launch_bounds__(256) void x3gemm(
    const u16* __restrict__ Ah0, const u16* __restrict__ Am0, const u16* __restrict__ Al0,
    const u16* __restrict__ Ah1, const u16* __restrict__ Am1, const u16* __restrict__ Al1,
    const u16* __restrict__ Bh, const u16* __restrict__ Bm, const u16* __restrict__ Bl,
    const float* __restrict__ bias0, const float* __restrict__ bias1,
    float* __restrict__ C0, float* __restrict__ C1,
    int K, int Nstride, int Mlim, int Nlim)
{
  __shared__ u16 lA[PLANES][64 * 32];
  __shared__ u16 lB[PLANES][64 * 32];
  const int zz = blockIdx.z;
  const u16* Ap[3] = { zz ? Ah1 : Ah0, zz ? Am1 : Am0, zz ? Al1 : Al0 };
  const u16* Bp[3] = {Bh, Bm, Bl};
  const float* bias = zz ? bias1 : bias0;
  float* C = zz ? C1 : C0;
  const int tid = threadIdx.x;
  const int wave = tid >> 6, lane = tid & 63;
  const int wr = wave >> 1, wc = wave & 1;
  const int row0 = blockIdx.y * 64, col0 = blockIdx.x * 64;

  f32x4 acc[2][2];
#pragma unroll
  for (int m = 0; m < 2; ++m)
#pragma unroll
    for (int n = 0; n < 2; ++n) acc[m][n] = (f32x4){0.f, 0.f, 0.f, 0.f};

  const int srow = lane >> 2, sslot = lane & 3;
  const int r15 = lane & 15, kq = lane >> 4;

  for (int k0 = 0; k0 < K; k0 += 32) {
    const int row = wave * 16 + srow;
    const int kg = sslot ^ ((row >> 1) & 3);
#pragma unroll
    for (int p = 0; p < PLANES; ++p) {
      gl2lds16(Ap[p] + (size_t)(row0 + row) * K + k0 + kg * 8, (u16*)lA[p] + wave * 512);
      gl2lds16(Bp[p] + (size_t)(col0 + row) * K + k0 + kg * 8, (u16*)lB[p] + wave * 512);
    }
    __syncthreads();
    short8 a[PLANES][2], b[PLANES][2];
#pragma unroll
    for (int m = 0; m < 2; ++m) {
      const int rowL = wr * 32 + m * 16 + r15;
      const int slot = kq ^ ((rowL >> 1) & 3);
#pragma unroll
      for (int p = 0; p < PLANES; ++p)
        a[p][m] = *reinterpret_cast<const short8*>(&lA[p][rowL * 32 + slot * 8]);
    }
#pragma unroll
    for (int n = 0; n < 2; ++n) {
      const int colL = wc * 32 + n * 16 + r15;
      const int slot = kq ^ ((colL >> 1) & 3);
#pragma unroll
      for (int p = 0; p < PLANES; ++p)
        b[p][n] = *reinterpret_cast<const short8*>(&lB[p][colL * 32 + slot * 8]);
    }
#pragma unroll
    for (int m = 0; m < 2; ++m)
#pragma unroll
      for (int n = 0; n < 2; ++n) {
        if constexpr (PLANES == 3) {
          acc[m][n] = __builtin_amdgcn_mfma_f32_16x16x32_bf16(a[2][m], b[0][n], acc[m][n], 0, 0, 0);
          acc[m][n] = __builtin_amdgcn_mfma_f32_16x16x32_bf16(a[0][m], b[2][n], acc[m][n], 0, 0, 0);
          acc[m][n] = __builtin_amdgcn_mfma_f32_16x16x32_bf16(a[1][m], b[1][n], acc[m][n], 0, 0, 0);
          acc[m][n] = __builtin_amdgcn_mfma_f32_16x16x32_bf16(a[1][m], b[0][n], acc[m][n], 0, 0, 0);
          acc[m][n] = __builtin_amdgcn_mfma_f32_16x16x32_bf16(a[0][m], b[1][n], acc[m][n], 0, 0, 0);
          acc[m][n] = __builtin_amdgcn_mfma_f32_16x16x32_bf16(a[0][m], b[0][n], acc[m][n], 0, 0, 0);
        } else {
          acc[m][n] = __builtin_amdgcn_mfma_f32_16x16x32_bf16(a[0][m], b[0][n], acc[m][n], 0, 0, 0);
        }
      }
    __syncthreads();
  }
  const int quad = lane >> 4;
#pragma unroll
  for (int m = 0; m < 2; ++m)
#pragma unroll
    for (int n = 0; n < 2; ++n) {
      const int cg = col0 + wc * 32 + n * 16 + r15;
      if (cg >= Nlim) continue;
      const float ev = bias ? bias[cg] : 0.f;
#pragma unroll
      for (int reg = 0; reg < 4; ++reg) {
        const int rg = row0 + wr * 32 + m * 16 + quad * 4 + reg;
        if (rg < Mlim) C[(size_t)rg * Nstride + cg] = acc[m][n][reg] + ev;
      }
    }
}

// ============ scores MFMA (128x128, BK=32, XCD-swizzled) ============
// Kt = key((A@B^T + cvec)/32) with mask applied in epilogue; masked/pad -> key 0.
__global__ __launch_bounds__(256) void mfma_scores128(
    const u16* __restrict__ A, const u16* __restrict__ B,
    const float* __restrict__ cvec, const unsigned long long* __restrict__ fbits,
    const unsigned* __restrict__ fij, u16* __restrict__ Kt, int K, int Nlim)
{
  __shared__ u16 ldsA[128 * 32];
  __shared__ u16 ldsB[128 * 32];
  const int tid = threadIdx.x;
  const int wave = tid >> 6, lane = tid & 63;
  const int wr = wave >> 1, wc = wave & 1;
  unsigned wg = blockIdx.y * gridDim.x + blockIdx.x;
  const unsigned per = (gridDim.x * gridDim.y) >> 3;
  wg = (wg & 7) * per + (wg >> 3);
  const int row0 = (int)(wg / gridDim.x) * 128, col0 = (int)(wg % gridDim.x) * 128;

  f32x4 acc[4][4];
#pragma unroll
  for (int m = 0; m < 4; ++m)
#pragma unroll
    for (int n = 0; n < 4; ++n) acc[m][n] = (f32x4){0.f, 0.f, 0.f, 0.f};

  const int srow = lane >> 2, sslot = lane & 3;

  for (int k0 = 0; k0 < K; k0 += 32) {
#pragma unroll
    for (int j = 0; j < 2; ++j) {
      const int row = (wave * 2 + j) * 16 + srow;
      const int kg = sslot ^ ((row >> 1) & 3);
      gl2lds16(A + (size_t)(row0 + row) * K + k0 + kg * 8, (char*)ldsA + (size_t)(wave * 2 + j) * 1024);
      gl2lds16(B + (size_t)(col0 + row) * K + k0 + kg * 8, (char*)ldsB + (size_t)(wave * 2 + j) * 1024);
    }
    __syncthreads();
    const int r15 = lane & 15, kq = lane >> 4;
    short8 a[4], b[4];
#pragma unroll
    for (int m = 0; m < 4; ++m) {
      const int rowL = wr * 64 + m * 16 + r15;
      const int slot = kq ^ ((rowL >> 1) & 3);
      a[m] = *reinterpret_cast<const short8*>(&ldsA[rowL * 32 + slot * 8]);
    }
#pragma unroll
    for (int n = 0; n < 4; ++n) {
      const int colL = wc * 64 + n * 16 + r15;
      const int slot = kq ^ ((colL >> 1) & 3);
      b[n] = *reinterpret_cast<const short8*>(&ldsB[colL * 32 + slot * 8]);
    }
#pragma unroll
    for (int m = 0; m < 4; ++m)
#pragma unroll
      for (int n = 0; n < 4; ++n)
        acc[m][n] = __builtin_amdgcn_mfma_f32_16x16x32_bf16(a[m], b[n], acc[m][n], 0, 0, 0);
    __syncthreads();
  }
  const int r15 = lane & 15, quad = lane >> 4;
#pragma unroll
  for (int m = 0; m < 4; ++m) {
    const int rgb = row0 + wr * 64 + m * 16 + quad * 4;
    unsigned long long fbr[4];
#pragma unroll
    for (int reg = 0; reg < 4; ++reg) fbr[reg] = fbits[rgb + reg];
#pragma unroll
    for (int n = 0; n < 4; ++n) {
      const int cg = col0 + wc * 64 + n * 16 + r15;
      const bool vc = (cg < Nlim);
      const float cv = vc ? cvec[cg] : 0.f;
      const unsigned pp = vc ? fij[cg] : 0u;
      const unsigned fi = pp & 63u, fj = pp >> 16;
#pragma unroll
      for (int reg = 0; reg < 4; ++reg) {
        u16 okey = 0;
        if (vc && ((((fbr[reg] >> fi) & (fbr[reg] >> fj)) & 1ULL) != 0)) {
          const float s = (acc[m][n][reg] + cv) * 0.03125f;
          const u16 u = f2bf(s);
          okey = (u & 0x8000) ? (u16)(~u) : (u16)(u | 0x8000);
        }
        Kt[(size_t)(rgb + reg) * NPAD + cg] = okey;
      }
    }
  }
}

// ================= decompose / conv helpers =================
__global__ __launch_bounds__(256) void decompose3(
    const float* __restrict__ in, u16* __restrict__ H, u16* __restrict__ M, u16* __restrict__ L,
    long n4_total, long n4_valid)
{
  for (long i = blockIdx.x * 256 + threadIdx.x; i < n4_total; i += (long)gridDim.x * 256) {
    u16 oh[4] = {0,0,0,0}, om[4] = {0,0,0,0}, ol[4] = {0,0,0,0};
    if (i < n4_valid) {
      const float4 f = *reinterpret_cast<const float4*>(in + i * 4);
      const float xs[4] = {f.x, f.y, f.z, f.w};
#pragma unroll
      for (int t = 0; t < 4; ++t) {
        const float x = xs[t];
        const u16 h = f2bf(x);       const float r1 = x - bf2f(h);
        const u16 m = f2bf(r1);      const float r2 = r1 - bf2f(m);
        const u16 l = f2bf(r2);
        oh[t] = h; om[t] = m; ol[t] = l;
      }
    }
    *reinterpret_cast<ulong1*>(H + i * 4) = *reinterpret_cast<ulong1*>(oh);
    *reinterpret_cast<ulong1*>(M + i * 4) = *reinterpret_cast<ulong1*>(om);
    *reinterpret_cast<ulong1*>(L + i * 4) = *reinterpret_cast<ulong1*>(ol);
  }
}

// z-batched transpose-decompose: z picks (in, out-planes). [R,C] f32 -> [C,R] bf16 x3.
__global__ __launch_bounds__(256) void decomposeT2(
    const float* __restrict__ in0, u16* __restrict__ H0, u16* __restrict__ M0, u16* __restrict__ L0,
    const float* __restrict__ in1, u16* __restrict__ H1, u16* __restrict__ M1, u16* __restrict__ L1,
    int R, int C)
{
  __shared__ float t[32][33];
  const float* in = blockIdx.z ? in1 : in0;
  u16* H = blockIdx.z ? H1 : H0;
  u16* M = blockIdx.z ? M1 : M0;
  u16* L = blockIdx.z ? L1 : L0;
  const int x = threadIdx.x & 31, y = threadIdx.x >> 5;
  const int bx = blockIdx.x, by = blockIdx.y;
#pragma unroll
  for (int yy = 0; yy < 4; ++yy)
    t[y + yy * 8][x] = in[(size_t)(by * 32 + y + yy * 8) * C + bx * 32 + x];
  __syncthreads();
#pragma unroll
  for (int yy = 0; yy < 4; ++yy) {
    const float v = t[x][y + yy * 8];
    const u16 h = f2bf(v);      const float r1 = v - bf2f(h);
    const u16 m = f2bf(r1);     const float r2 = r1 - bf2f(m);
    const u16 l = f2bf(r2);
    const size_t o = (size_t)(bx * 32 + y + yy * 8) * R + by * 32 + x;
    H[o] = h; M[o] = m; L[o] = l;
  }
}

// two-segment f32->bf16 conversion (zero-pad beyond valid)
__global__ __launch_bounds__(256) void conv2seg(
    const float* __restrict__ inA, u16* __restrict__ outA, long nb_a, long n4a_valid,
    const float* __restrict__ inB, u16* __restrict__ outB)
{
  const long b = blockIdx.x;
  const float* in; u16* out; long i;
  bool valid = true;
  if (b < nb_a) { in = inA; out = outA; i = b * 256 + threadIdx.x; valid = (i < n4a_valid); }
  else          { in = inB; out = outB; i = (b - nb_a) * 256 + threadIdx.x; }
  u16 o[4] = {0, 0, 0, 0};
  if (valid) {
    const float4 f = *reinterpret_cast<const float4*>(in + i * 4);
    o[0] = f2bf(f.x); o[1] = f2bf(f.y); o[2] = f2bf(f.z); o[3] = f2bf(f.w);
  }
  *reinterpret_cast<ulong1*>(out + i * 4) = *reinterpret_cast<ulong1*>(o);
}

__global__ __launch_bounds__(256) void conv_bf16(
    const float* __restrict__ in, u16* __restrict__ out, long n4)
{
  for (long i = blockIdx.x * 256 + threadIdx.x; i < n4; i += (long)gridDim.x * 256) {
    const float4 f = *reinterpret_cast<const float4*>(in + i * 4);
    u16 o[4] = {f2bf(f.x), f2bf(f.y), f2bf(f.z), f2bf(f.w)};
    *reinterpret_cast<ulong1*>(out + i * 4) = *reinterpret_cast<ulong1*>(o);
  }
}

// ================= bias-vector prologue kernels =================
__global__ __launch_bounds__(256) void dual_rowdot(
    const float* __restrict__ Wk, const float* __restrict__ bq,
    const float* __restrict__ Wv, const float* __restrict__ bt, const float* __restrict__ bv,
    float* __restrict__ u1, float* __restrict__ cvv)
{
  const int b = blockIdx.x;
  const int row = (b & 255) * 4 + (threadIdx.x >> 6);
  const int lane = threadIdx.x & 63;
  float acc = 0.f;
  if (b < 256) {
#pragma unroll
    for (int j = 0; j < 16; ++j)
      acc = fmaf(Wk[row + (size_t)(lane + j * 64) * HDIM], bq[lane + j * 64], acc);
  } else {
#pragma unroll
    for (int j = 0; j < 16; ++j)
      acc = fmaf(Wv[(size_t)row * HDIM + lane + j * 64], bt[lane + j * 64], acc);
  }
#pragma unroll
  for (int off = 32; off; off >>= 1) acc += __shfl_xor(acc, off);
  if (lane == 0) {
    if (b < 256) u1[row] = acc;
    else cvv[row] = acc + bv[row];
  }
}

__global__ __launch_bounds__(256) void u2_k(
    const float* __restrict__ Wt, const float* __restrict__ u1, float* __restrict__ u2)
{
  const int row = blockIdx.x * 4 + (threadIdx.x >> 6);
  const int lane = threadIdx.x & 63;
  float acc = 0.f;
#pragma unroll
  for (int j = 0; j < 16; ++j)
    acc = fmaf(Wt[row + (size_t)(lane + j * 64) * EDIM], u1[lane + j * 64], acc);
#pragma unroll
  for (int off = 32; off; off >>= 1) acc += __shfl_xor(acc, off);
  if (lane == 0) u2[row] = acc;
}

__global__ __launch_bounds__(256) void cvec_k(
    const float* __restrict__ rel, const float* __restrict__ u2,
    const float* __restrict__ u1, const float* __restrict__ bt,
    const float* __restrict__ bk, const float* __restrict__ bq, float* __restrict__ cvec)
{
  const int row = blockIdx.x * 4 + (threadIdx.x >> 6);
  const int lane = threadIdx.x & 63;
  if (row >= R_REL) return;
  float acc = 0.f;
#pragma unroll
  for (int j = 0; j < 12; ++j)
    acc = fmaf(rel[(size_t)row * EDIM + lane + j * 64], u2[lane + j * 64], acc);
  float sac = 0.f;
#pragma unroll
  for (int j = 0; j < 16; ++j) {
    const int k = lane + j * 64;
    sac = fmaf(bt[k], u1[k], sac);
    sac = fmaf(bk[k], bq[k], sac);
  }
  acc += sac;
#pragma unroll
  for (int off = 32; off; off >>= 1) acc += __shfl_xor(acc, off);
  if (lane == 0) cvec[row] = acc;
}

__global__ __launch_bounds__(256) void w2bias_k(
    const float* __restrict__ T1f, const float* __restrict__ Wq,
    const float* __restrict__ bt, const float* __restrict__ bk, float* __restrict__ w2bias)
{
  const int row = blockIdx.x * 4 + (threadIdx.x >> 6);
  const int lane = threadIdx.x & 63;
  float acc = 0.f;
#pragma unroll
  for (int j = 0; j < 16; ++j) {
    const int k = lane + j * 64;
    acc = fmaf(T1f[(size_t)row * HDIM + k], bt[k], acc);
    acc = fmaf(Wq[row + (size_t)k * HDIM], bk[k], acc);
  }
#pragma unroll
  for (int off = 32; off; off >>= 1) acc += __shfl_xor(acc, off);
  if (lane == 0) w2bias[row] = acc;
}

// ================= fbits (self-detecting mask kind) + fij pack =================
__global__ __launch_bounds__(256) void build_fbits(
    const void* __restrict__ mask, const int* __restrict__ f_i, const int* __restrict__ f_j,
    unsigned long long* __restrict__ fbits, unsigned* __restrict__ fij)
{
  const int gm = blockIdx.x * 4 + (threadIdx.x >> 6);
  const int lane = threadIdx.x & 63;
  const unsigned* mw = (const unsigned*)mask;
  bool sawf = false, sawg = false;
#pragma unroll
  for (int t = 0; t < 4; ++t) {
    const unsigned w = mw[lane * 4 + t];
    sawf |= (w == 0x3F800000u);
    sawg |= (w > 1u);
  }
  const int kind = __ballot(sawf) ? 2 : (__ballot(sawg) ? 1 : 0);
  const size_t e = (size_t)gm * 64 + lane;
  bool on;
  if (kind == 0)      on = ((const int*)mask)[e] != 0;
  else if (kind == 1) on = ((const unsigned char*)mask)[e] != 0;
  else                on = ((const float*)mask)[e] != 0.f;
  const unsigned long long b = __ballot(on);
  if (lane == 0) fbits[gm] = b;
  if (blockIdx.x < 8) {
    const int i = blockIdx.x * 256 + threadIdx.x;
    const int src = (i < R_REL) ? i : (R_REL - 1);
    fij[i] = ((unsigned)f_i[src] & 0xFFFFu) | (((unsigned)f_j[src] & 0xFFFFu) << 16);
  }
}

// ====== PHASE A: pure-stream radix prefilter -> candidate lists ======
__global__ __launch_bounds__(64) void prefilter_k(
    const u16* __restrict__ Kt, u16* __restrict__ candidx, int* __restrict__ ncands)
{
  const int gm = blockIdx.x;
  const int lane = threadIdx.x;
  unsigned key[32];
  const u16* rowp = Kt + (size_t)gm * NPAD;
#pragma unroll
  for (int L = 0; L < 4; ++L) {
    const short8 v = *reinterpret_cast<const short8*>(rowp + lane * 8 + L * 512);
#pragma unroll
    for (int r = 0; r < 8; ++r) key[L * 8 + r] = (unsigned)(u16)v[r];
  }
  // binary search largest T with count(key >= T) >= KSEL (keys pre-masked; 0 = inactive)
  int lo = 1, hi = 65536;
  while (hi - lo > 1) {
    const int mid = (lo + hi) >> 1;
    int cnt = 0;
#pragma unroll
    for (int j = 0; j < 32; ++j)
      cnt += __popcll(__ballot(key[j] >= (unsigned)mid));
    if (cnt >= KSEL) lo = mid; else hi = mid;
  }
  const unsigned T = (unsigned)lo;
  int base = 0;
#pragma unroll
  for (int L = 0; L < 4; ++L) {
#pragma unroll
    for (int r = 0; r < 8; ++r) {
      const int j = L * 8 + r;
      const bool c = key[j] >= T;
      const unsigned long long m = __ballot(c);
      const int pre = __builtin_amdgcn_mbcnt_hi((unsigned)(m >> 32),
                      __builtin_amdgcn_mbcnt_lo((unsigned)m, 0));
      const int slot = base + pre;
      if (c && slot < CAP) candidx[(size_t)gm * CAP + slot] = (u16)(lane * 8 + r + L * 512);
      base += __popcll(m);
    }
  }
  if (lane == 0) ncands[gm] = (base < CAP) ? base : CAP;
}

// ====== PHASE B: exact f32 rescore + bitonic top-28 + softmax ======
__global__ __launch_bounds__(64) void rescore_k(
    const u16* __restrict__ candidx, const int* __restrict__ ncands,
    const float* __restrict__ qh, const float* __restrict__ W2, const float* __restrict__ cvec,
    int* __restrict__ topidx, float* __restrict__ topw)
{
  const int gm = blockIdx.x;
  const int lane = threadIdx.x;
  const int ncand = ncands[gm];
  int myr = 0x7fffffff;
  if (lane < ncand) myr = candidx[(size_t)gm * CAP + lane];

  float q[16];
  {
    const float* qp = qh + (size_t)gm * HDIM + lane * 16;
#pragma unroll
    for (int v4 = 0; v4 < 4; ++v4) {
      const float4 f = *reinterpret_cast<const float4*>(qp + v4 * 4);
      q[v4 * 4 + 0] = f.x; q[v4 * 4 + 1] = f.y; q[v4 * 4 + 2] = f.z; q[v4 * 4 + 3] = f.w;
    }
  }
  float myscore = -INFINITY;
  for (int c = 0; c < CAP; ++c) {
    if (c >= ncand) break;
    const int r = __shfl(myr, c);
    const float* wp = W2 + (size_t)r * HDIM + lane * 16;
    float d = 0.f;
#pragma unroll
    for (int v4 = 0; v4 < 4; ++v4) {
      const float4 f = *reinterpret_cast<const float4*>(wp + v4 * 4);
      d = fmaf(q[v4 * 4 + 0], f.x, d);
      d = fmaf(q[v4 * 4 + 1], f.y, d);
      d = fmaf(q[v4 * 4 + 2], f.z, d);
      d = fmaf(q[v4 * 4 + 3], f.w, d);
    }
#pragma unroll
    for (int off = 32; off; off >>= 1) d += __shfl_xor(d, off);
    const float s = (d + cvec[r]) * 0.03125f;
    if (lane == c) myscore = s;
  }

  // bitonic sort 64 lanes, descending score, tie -> ascending index
#pragma unroll
  for (int k = 2; k <= 64; k <<= 1) {
#pragma unroll
    for (int j = k >> 1; j > 0; j >>= 1) {
      const float ov = __shfl_xor(myscore, j);
      const int oi = __shfl_xor(myr, j);
      const bool lower = (lane & j) == 0;
      const bool want_desc = (lane & k) == 0;
      const bool mine_better = (myscore > ov) || (myscore == ov && myr < oi);
      const bool keep = (lower == want_desc) ? mine_better : !mine_better;
      if (!keep) { myscore = ov; myr = oi; }
    }
  }

  const int nvalid = __popcll(__ballot(myscore > -INFINITY));
  const int nsel = (nvalid < TOPK) ? nvalid : TOPK;
  const float m0 = __shfl(myscore, 0);
  const float e = (lane < nsel) ? expf(myscore - m0) : 0.f;
  float z = e;
#pragma unroll
  for (int off = 32; off; off >>= 1) z += __shfl_xor(z, off);
  if (lane < TOPK) {
    topw[(size_t)gm * TOPK + lane] = (lane < nsel) ? (e / z) : 0.f;
    topidx[(size_t)gm * TOPK + lane] = (lane < nsel) ? myr : 0;
  }
}

// ====== PHASE C: sparse V-gather ======
__global__ __launch_bounds__(256) void out_gather(
    const int* __restrict__ topidx, const float* __restrict__ topw,
    const float* __restrict__ V, float* __restrict__ out)
{
  const int gm = blockIdx.x;
  const int tid = threadIdx.x;
  __shared__ float w[TOPK];
  __shared__ int   id[TOPK];
  if (tid < TOPK) {
    w[tid] = topw[(size_t)gm * TOPK + tid];
    id[tid] = topidx[(size_t)gm * TOPK + tid];
  }
  __syncthreads();
  float4 acc = make_float4(0.f, 0.f, 0.f, 0.f);
#pragma unroll 4
  for (int i = 0; i < TOPK; ++i) {
    const float wi = w[i];
    const float4 v = *reinterpret_cast<const float4*>(V + (size_t)id[i] * HDIM + tid * 4);
    acc.x = fmaf(wi, v.x, acc.x);
    acc.y = fmaf(wi, v.y, acc.y);
    acc.z = fmaf(wi, v.z, acc.z);
    acc.w = fmaf(wi, v.w, acc.w);
  }
  *reinterpret_cast<float4*>(out + (size_t)gm * HDIM + tid * 4) = acc;
}

extern "C" void kernel_launch(void* const* d_in, const int* in_sizes, int n_in,
                              void* d_out, int out_size, void* d_ws, size_t ws_size,
                              hipStream_t stream) {
  const float* qh  = (const float*)d_in[0];
  const void*  mask = d_in[1];
  const float* rel = (const float*)d_in[2];
  const int* f_i = (const int*)d_in[3];
  const int* f_j = (const int*)d_in[4];
  const float* Wt = (const float*)d_in[5]; const float* bt = (const float*)d_in[6];
  const float* Wq = (const float*)d_in[7]; const float* bq = (const float*)d_in[8];
  const float* Wk = (const float*)d_in[9]; const float* bk = (const float*)d_in[10];
  const float* Wv = (const float*)d_in[11]; const float* bv = (const float*)d_in[12];
  float* out = (float*)d_out;

  // ---- workspace layout with lifetime-based aliasing ----
  char* p = (char*)d_ws;
  auto alloc = [&](size_t bytes) { char* q_ = p; p += (bytes + 255) & ~(size_t)255; return q_; };
  float* W2   = (float*)alloc((size_t)R_REL * HDIM * 4);
  char* strip = alloc((size_t)(1024*1024 + 1024*768 + 1024*768) * 4);
  float* T1f = (float*)strip;
  float* Pf  = T1f + 1024 * 1024;
  float* Pvf = Pf + 1024 * 768;
  float* Vm  = (float*)strip;                   // alias (written after T1f/Pf/Pvf dead)
  u16* R1 = (u16*)alloc((size_t)3 * 1024 * 1024 * 2);   // WqT planes -> T1 planes
  u16* R2 = (u16*)alloc((size_t)3 * 1024 * 1024 * 2);   // WkT planes -> P planes
  u16* WtTp = (u16*)alloc((size_t)3 * 768 * 1024 * 2);
  u16* relp = (u16*)alloc((size_t)3 * MPADR * EDIM * 2);
  u16* qhb  = (u16*)alloc((size_t)MROWS * HDIM * 2);
  char* w2b_region = alloc((size_t)NPAD * HDIM * 2);
  u16* W2b  = (u16*)w2b_region;
  u16* Pv16 = (u16*)alloc((size_t)1024 * 768 * 2);
  u16* Kt   = (u16*)alloc((size_t)MROWS * NPAD * 2);
  u16* R3   = Kt;                               // Wv planes (dead before Kt written)
  u16* candidx = (u16*)alloc((size_t)MROWS * CAP * 2);
  int* ncands  = (int*)alloc((size_t)MROWS * 4);
  float* cvec   = (float*)alloc(NPAD * 4);
  float* u1     = (float*)alloc(1024 * 4);
  float* u2     = (float*)alloc(1024 * 4);
  float* w2bias = (float*)alloc(1024 * 4);
  float* cvv    = (float*)alloc(1024 * 4);
  unsigned long long* fbits = (unsigned long long*)alloc((size_t)MROWS * 8);
  unsigned* fij = (unsigned*)alloc(NPAD * 4);
  int* tidx = (int*)w2b_region;                 // alias (W2b dead after scores)
  float* tw = (float*)(w2b_region + (size_t)MROWS * TOPK * 4);

  const size_t PL1 = (size_t)1024 * 1024;
  const size_t PLW = (size_t)768 * 1024;
  const size_t PLR = (size_t)MPADR * EDIM;
  const size_t PLP = (size_t)1024 * 768;

  const dim3 blk(256);

  // fbits (self-detecting) + fij
  build_fbits<<<dim3(MROWS / 4), blk, 0, stream>>>(mask, f_i, f_j, fbits, fij);

  // weight decompositions
  decomposeT2<<<dim3(1024/32, 1024/32, 2), blk, 0, stream>>>(
      Wq, R1, R1+PL1, R1+2*PL1, Wk, R2, R2+PL1, R2+2*PL1, 1024, 1024);
  decomposeT2<<<dim3(768/32, 1024/32, 1), blk, 0, stream>>>(
      Wt, WtTp, WtTp+PLW, WtTp+2*PLW, nullptr, nullptr, nullptr, nullptr, 1024, 768);
  decompose3<<<dim3(1024), blk, 0, stream>>>(rel, relp, relp+PLR, relp+2*PLR,
                                             (long)MPADR*EDIM/4, (long)R_REL*EDIM/4);
  decompose3<<<dim3(1024), blk, 0, stream>>>(Wv, R3, R3+PL1, R3+2*PL1, (long)PL1/4, (long)PL1/4);
  conv_bf16<<<dim3(2048), blk, 0, stream>>>(qh, qhb, (long)MROWS*HDIM/4);

  // bias-vector chain
  dual_rowdot<<<dim3(512), blk, 0, stream>>>(Wk, bq, Wv, bt, bv, u1, cvv);
  u2_k<<<dim3(192), blk, 0, stream>>>(Wt, u1, u2);
  cvec_k<<<dim3((R_REL + 3) / 4), blk, 0, stream>>>(rel, u2, u1, bt, bk, bq, cvec);

  // T1 = Wq^T @ Wk  (bf16x3)
  x3gemm<3><<<dim3(1024/64, 1024/64, 1), blk, 0, stream>>>(
      R1, R1+PL1, R1+2*PL1, nullptr, nullptr, nullptr,
      R2, R2+PL1, R2+2*PL1, nullptr, nullptr, T1f, nullptr, 1024, 1024, 1024, 1024);
  w2bias_k<<<dim3(256), blk, 0, stream>>>(T1f, Wq, bt, bk, w2bias);
  decompose3<<<dim3(1024), blk, 0, stream>>>(T1f, R1, R1+PL1, R1+2*PL1, (long)PL1/4, (long)PL1/4);
  // P = T1 @ Wt  and  Pv = Wv @ Wt  (z-batched, shared B = WtT planes)
  x3gemm<3><<<dim3(768/64, 1024/64, 2), blk, 0, stream>>>(
      R1, R1+PL1, R1+2*PL1, R3, R3+PL1, R3+2*PL1,
      WtTp, WtTp+PLW, WtTp+2*PLW, nullptr, nullptr, Pf, Pvf, 1024, 768, 1024, 768);
  decompose3<<<dim3(1024), blk, 0, stream>>>(Pf, R2, R2+PLP, R2+2*PLP, (long)PLP/4, (long)PLP/4);
  // W2 = rel @ P^T + w2bias
  x3gemm<3><<<dim3(1024/64, MPADR/64, 1), blk, 0, stream>>>(
      relp, relp+PLR, relp+2*PLR, nullptr, nullptr, nullptr,
      R2, R2+PLP, R2+2*PLP, w2bias, nullptr, W2, nullptr, EDIM, HDIM, R_REL, HDIM);

  // W2b (padded) + Pv16 conversions in one launch
  conv2seg<<<dim3(2048 + 768), blk, 0, stream>>>(
      W2, W2b, 2048, (long)R_REL*HDIM/4, Pvf, Pv16);

  // Vm = rel_h @ Pv16^T + cvv  (bf16; aliases the dead f32 strip)
  x3gemm<1><<<dim3(1024/64, MPADR/64, 1), blk, 0, stream>>>(
      relp, nullptr, nullptr, nullptr, nullptr, nullptr,
      Pv16, nullptr, nullptr, cvv, nullptr, Vm, nullptr, EDIM, HDIM, R_REL, HDIM);

  // approx score keys, masked in epilogue (overwrites R3 region — Wv planes dead)
  mfma_scores128<<<dim3(NPAD/128, MROWS/128), blk, 0, stream>>>(
      qhb, W2b, cvec, fbits, fij, Kt, HDIM, R_REL);

  // A: pure-stream prefilter
  prefilter_k<<<dim3(MROWS), dim3(64), 0, stream>>>(Kt, candidx, ncands);
  // B: exact rescore + top-28 + softmax (no Kt stream -> W2 stays cached)
  rescore_k<<<dim3(MROWS), dim3(64), 0, stream>>>(candidx, ncands, qh, W2, cvec, tidx, tw);
  // C: sparse V-gather
  out_gather<<<dim3(MROWS), blk, 0, stream>>>(tidx, tw, Vm, out);
}